// Round 21
// baseline (65663.892 us; speedup 1.0000x reference)
//
#include <hip/hip_runtime.h>

#define NODES 1024
#define LAYERS 5
#define SEQ 2048
#define IN_DIM 30
#define OUT_DIM 12
#define SLOPE 0.01f
#define RING_D 16

typedef unsigned long long u64;

__device__ __forceinline__ float sigmoidf_(float x) { return 1.0f / (1.0f + expf(-x)); }

// ---------------- FC1: concat(sim,real,act) @ W1^T + b1, leaky ----------------
__global__ __launch_bounds__(256) void fc1_kernel(
    const float* __restrict__ sim, const float* __restrict__ realv,
    const float* __restrict__ act, const float* __restrict__ W1,
    const float* __restrict__ b1, float* __restrict__ x_out)
{
    int t = blockIdx.x;
    __shared__ float in_s[IN_DIM];
    int tid = threadIdx.x;
    if (tid < 12) in_s[tid] = sim[t * 12 + tid];
    else if (tid < 24) in_s[tid] = realv[t * 12 + (tid - 12)];
    else if (tid < 30) in_s[tid] = act[t * 6 + (tid - 24)];
    __syncthreads();
    for (int n = tid; n < NODES; n += 256) {
        float acc = b1[n];
        const float* w = W1 + n * IN_DIM;
        #pragma unroll
        for (int k = 0; k < IN_DIM; ++k) acc += w[k] * in_s[k];
        x_out[t * NODES + n] = acc > 0.f ? acc : SLOPE * acc;
    }
}

// ---------------- xproj: XP = X @ W^T + (b_ih + b_hh) ----------------
#define BM 64
#define BN 64
#define BK 16

__global__ __launch_bounds__(256) void xproj_kernel(
    const float* __restrict__ X, const float* __restrict__ W,
    const float* __restrict__ bih, const float* __restrict__ bhh,
    float* __restrict__ XP)
{
    const int GN = 4 * NODES;
    int bm = blockIdx.y;
    int bn = blockIdx.x;
    __shared__ float As[BK][BM];
    __shared__ float Bs[BK][BN];
    int tid = threadIdx.x;
    int tx = tid % 16, ty = tid / 16;
    int arow = tid / 4;
    int acol4 = (tid % 4) * 4;
    float acc[4][4] = {};

    for (int k0 = 0; k0 < NODES; k0 += BK) {
        float4 a = *(const float4*)&X[(size_t)(bm * BM + arow) * NODES + k0 + acol4];
        As[acol4 + 0][arow] = a.x; As[acol4 + 1][arow] = a.y;
        As[acol4 + 2][arow] = a.z; As[acol4 + 3][arow] = a.w;
        float4 b = *(const float4*)&W[(size_t)(bn * BN + arow) * NODES + k0 + acol4];
        Bs[acol4 + 0][arow] = b.x; Bs[acol4 + 1][arow] = b.y;
        Bs[acol4 + 2][arow] = b.z; Bs[acol4 + 3][arow] = b.w;
        __syncthreads();
        #pragma unroll
        for (int k = 0; k < BK; ++k) {
            float ra[4], rb[4];
            #pragma unroll
            for (int m = 0; m < 4; ++m) ra[m] = As[k][ty * 4 + m];
            #pragma unroll
            for (int n = 0; n < 4; ++n) rb[n] = Bs[k][tx * 4 + n];
            #pragma unroll
            for (int m = 0; m < 4; ++m)
                #pragma unroll
                for (int n = 0; n < 4; ++n)
                    acc[m][n] += ra[m] * rb[n];
        }
        __syncthreads();
    }
    #pragma unroll
    for (int m = 0; m < 4; ++m) {
        int t = bm * BM + ty * 4 + m;
        int g0 = bn * BN + tx * 4;
        float4 o;
        o.x = acc[m][0] + bih[g0 + 0] + bhh[g0 + 0];
        o.y = acc[m][1] + bih[g0 + 1] + bhh[g0 + 1];
        o.z = acc[m][2] + bih[g0 + 2] + bhh[g0 + 2];
        o.w = acc[m][3] + bih[g0 + 3] + bhh[g0 + 3];
        *(float4*)&XP[(size_t)t * GN + g0] = o;
    }
}

// ---------------- Fused LSTM group (NL = 1..3): R16 protocol + NL3 resource plan ----------
// 256 blocks x NL*4 waves, cooperative, free-running. Wave w: lg=w>>2, q=w&3,
// unit j=blockIdx.x*4+q; l=l_base+lg.
// Protocol == R16 (PASSED): lg0 consumes XP; lg>=1 read x(t) from mir[lg-1] flag
// t+1 (LDS). Each lg quarter-polls its own global ring, mirrors into mir[lg]
// (parity-2). GATE (lg<NL-1, t>=2): wait mir[lg+1] flags >= t-2 before
// overwriting mir[lg][t&1]. FINAL FILL (lg<NL-1): gate >= SEQ-2, then mirror
// ring flag SEQ. Chain acyclic (R16 pairwise-proven; R17 ran depth-4 correctly).
// R21 resource fixes (R20's failure was VGPR=84 -> spill, WRITE_SIZE 2.2GB):
//  (1) deepest layer's Whh in LDS (64KB) -- removes 64 regs + 16MB/step restream;
//  (2) mirror reads in TWO 8-slot chunks -- live poll buffers 8+4 u64, no spill.
__global__ __launch_bounds__(768, 3)
void lstm_group_kernel(
    const float* __restrict__ Wih,   // [L][4N][N] (global base)
    const float* __restrict__ Whh,   // [L][4N][N] (global base)
    const float* __restrict__ bih,   // [L][4N]
    const float* __restrict__ bhh,   // [L][4N]
    const float* __restrict__ XP,    // [SEQ][4N] first-group-layer input proj
    const float* __restrict__ h0,    // [L][N]
    const float* __restrict__ c0,    // [L][N]
    float* __restrict__ Yout,        // [SEQ][N] last-group-layer output
    u64* rings, int l_base, int NL)
{
    __shared__ u64 mir[3][2][16][64];        // 48KB
    __shared__ float whh_lds[4][4][NODES];   // 64KB (used by lg==2 of NL3)

    const int tid = threadIdx.x;
    const int wave = tid >> 6, lane = tid & 63;
    const int lg = wave >> 2;
    const int q = wave & 3;
    const int j = blockIdx.x * 4 + q;
    const int l = l_base + lg;
    const bool first = (lg == 0);
    const bool last  = (lg == NL - 1);
    const bool lds_whh = (NL == 3 && lg == 2);

    // ---- stage Whh: LDS for the deepest NL3 layer, registers otherwise ----
    float whh[4][16];
    if (lds_whh) {
        const float* wp = Whh + (size_t)l * 4 * NODES * NODES;
        #pragma unroll
        for (int g = 0; g < 4; ++g) {
            const float* src = wp + (size_t)(g * NODES + j) * NODES;
            float* dst = whh_lds[q][g];
            #pragma unroll
            for (int v = 0; v < 4; ++v) {
                int idx = (lane + v * 64) * 4;
                *(float4*)&dst[idx] = *(const float4*)&src[idx];
            }
        }
    } else {
        const float* wp = Whh + (size_t)l * 4 * NODES * NODES;
        #pragma unroll
        for (int g = 0; g < 4; ++g)
            #pragma unroll
            for (int k = 0; k < 16; ++k)
                whh[g][k] = wp[(size_t)(g * NODES + j) * NODES + lane + k * 64];
    }
    float wih[4][16];
    if (!first) {
        const float* wp = Wih + (size_t)l * 4 * NODES * NODES;
        #pragma unroll
        for (int g = 0; g < 4; ++g)
            #pragma unroll
            for (int k = 0; k < 16; ++k)
                wih[g][k] = wp[(size_t)(g * NODES + j) * NODES + lane + k * 64];
    }
    float bg[4] = {0.f, 0.f, 0.f, 0.f};
    if (!first) {
        #pragma unroll
        for (int g = 0; g < 4; ++g)
            bg[g] = bih[l * 4 * NODES + g * NODES + j] + bhh[l * 4 * NODES + g * NODES + j];
    }

    // zero LDS mirrors (stale flags would fake a match)
    for (int idx = tid; idx < 3 * 2 * 16 * 64; idx += blockDim.x)
        ((u64*)mir)[idx] = 0;

    u64* ring_own = rings + (size_t)l * RING_D * NODES;

    float c = c0[l * NODES + j];
    float xpg[4] = {0.f, 0.f, 0.f, 0.f};
    if (first) {
        #pragma unroll
        for (int g = 0; g < 4; ++g) xpg[g] = XP[(size_t)0 * 4 * NODES + g * NODES + j];
    }
    __syncthreads();  // mirrors zeroed + whh_lds staged

    for (int t = 0; t < SEQ; ++t) {
        float gate[4] = {0.f, 0.f, 0.f, 0.f};

        // ---- own-layer h(t-1): quarter-poll global -> [gate] -> mirror -> chunked read ----
        if (t == 0) {
            #pragma unroll
            for (int k = 0; k < 16; ++k) {
                float hh = h0[l * NODES + lane + k * 64];
                if (lds_whh) {
                    #pragma unroll
                    for (int g = 0; g < 4; ++g) gate[g] += whh_lds[q][g][lane + k * 64] * hh;
                } else {
                    #pragma unroll
                    for (int g = 0; g < 4; ++g) gate[g] += whh[g][k] * hh;
                }
            }
        } else {
            u64* so = ring_own + (size_t)(t % RING_D) * NODES;
            const int par = t & 1;
            u64 mybuf[4];
            for (;;) {
                #pragma unroll
                for (int kk = 0; kk < 4; ++kk)
                    mybuf[kk] = __hip_atomic_load(&so[lane + (q * 4 + kk) * 64],
                                                  __ATOMIC_RELAXED, __HIP_MEMORY_SCOPE_AGENT);
                bool ok = true;
                #pragma unroll
                for (int kk = 0; kk < 4; ++kk) ok = ok && ((int)(mybuf[kk] >> 32) == t);
                if (ok) break;
            }
            // gate: protect downstream's pending x-read of flag t-2 (same parity)
            if (!last && t >= 2) {
                const int thresh = t - 2;
                for (;;) {
                    bool ok = true;
                    #pragma unroll
                    for (int qq = 0; qq < 4; ++qq) {
                        u64 v = __hip_atomic_load(&mir[lg + 1][par][qq * 4][lane],
                                                  __ATOMIC_RELAXED, __HIP_MEMORY_SCOPE_WORKGROUP);
                        ok = ok && ((int)(v >> 32) >= thresh);
                    }
                    if (ok) break;
                }
            }
            #pragma unroll
            for (int kk = 0; kk < 4; ++kk)
                __hip_atomic_store(&mir[lg][par][q * 4 + kk][lane], mybuf[kk],
                                   __ATOMIC_RELAXED, __HIP_MEMORY_SCOPE_WORKGROUP);
            // chunked full read: two 8-slot halves (caps live u64 regs at 8)
            #pragma unroll
            for (int half = 0; half < 2; ++half) {
                u64 vo[8];
                for (;;) {
                    bool ok = true;
                    #pragma unroll
                    for (int k = 0; k < 8; ++k) {
                        vo[k] = __hip_atomic_load(&mir[lg][par][half * 8 + k][lane],
                                                  __ATOMIC_RELAXED, __HIP_MEMORY_SCOPE_WORKGROUP);
                        ok = ok && ((int)(vo[k] >> 32) == t);
                    }
                    if (ok) break;
                }
                #pragma unroll
                for (int k = 0; k < 8; ++k) {
                    float hh = __uint_as_float((unsigned)vo[k]);
                    const int kk = half * 8 + k;
                    if (lds_whh) {
                        #pragma unroll
                        for (int g = 0; g < 4; ++g)
                            gate[g] += whh_lds[q][g][lane + kk * 64] * hh;
                    } else {
                        #pragma unroll
                        for (int g = 0; g < 4; ++g) gate[g] += whh[g][kk] * hh;
                    }
                }
            }
        }

        // ---- prev-layer x(t) = upstream mirror flag t+1 (pure LDS, chunked) ----
        if (!first) {
            const int par = (t + 1) & 1;
            #pragma unroll
            for (int half = 0; half < 2; ++half) {
                u64 vi[8];
                for (;;) {
                    bool ok = true;
                    #pragma unroll
                    for (int k = 0; k < 8; ++k) {
                        vi[k] = __hip_atomic_load(&mir[lg - 1][par][half * 8 + k][lane],
                                                  __ATOMIC_RELAXED, __HIP_MEMORY_SCOPE_WORKGROUP);
                        ok = ok && ((int)(vi[k] >> 32) == t + 1);
                    }
                    if (ok) break;
                }
                #pragma unroll
                for (int k = 0; k < 8; ++k) {
                    float xx = __uint_as_float((unsigned)vi[k]);
                    const int kk = half * 8 + k;
                    #pragma unroll
                    for (int g = 0; g < 4; ++g) gate[g] += wih[g][kk] * xx;
                }
            }
        }

        // ---- reduce + activations ----
        #pragma unroll
        for (int g = 0; g < 4; ++g) {
            float acc = gate[g];
            #pragma unroll
            for (int off = 32; off > 0; off >>= 1) acc += __shfl_xor(acc, off);
            gate[g] = acc + (first ? xpg[g] : bg[g]);
        }

        float ig = sigmoidf_(gate[0]);
        float fg = sigmoidf_(gate[1]);
        float gg = tanhf(gate[2]);
        float og = sigmoidf_(gate[3]);
        c = fg * c + ig * gg;
        float h = og * tanhf(c);

        if (lane == 0) {
            u64 pv = ((u64)(unsigned)(t + 1) << 32) | (u64)__float_as_uint(h);
            __hip_atomic_store(&ring_own[(size_t)((t + 1) % RING_D) * NODES + j], pv,
                               __ATOMIC_RELAXED, __HIP_MEMORY_SCOPE_AGENT);
            if (last) Yout[(size_t)t * NODES + j] = h;
        }

        if (first && t + 1 < SEQ) {
            #pragma unroll
            for (int g = 0; g < 4; ++g)
                xpg[g] = XP[(size_t)(t + 1) * 4 * NODES + g * NODES + j];
        }
    }

    // ---- FINAL FILL (each non-last layer): mirror ring flag SEQ for downstream ----
    if (!last) {
        const int par = SEQ & 1;
        const int thresh = SEQ - 2;
        for (;;) {  // gate: downstream past its x-read of flag SEQ-2
            bool ok = true;
            #pragma unroll
            for (int qq = 0; qq < 4; ++qq) {
                u64 v = __hip_atomic_load(&mir[lg + 1][par][qq * 4][lane],
                                          __ATOMIC_RELAXED, __HIP_MEMORY_SCOPE_WORKGROUP);
                ok = ok && ((int)(v >> 32) >= thresh);
            }
            if (ok) break;
        }
        u64* so = ring_own + (size_t)(SEQ % RING_D) * NODES;
        u64 mybuf[4];
        for (;;) {
            #pragma unroll
            for (int kk = 0; kk < 4; ++kk)
                mybuf[kk] = __hip_atomic_load(&so[lane + (q * 4 + kk) * 64],
                                              __ATOMIC_RELAXED, __HIP_MEMORY_SCOPE_AGENT);
            bool ok = true;
            #pragma unroll
            for (int kk = 0; kk < 4; ++kk) ok = ok && ((int)(mybuf[kk] >> 32) == SEQ);
            if (ok) break;
        }
        #pragma unroll
        for (int kk = 0; kk < 4; ++kk)
            __hip_atomic_store(&mir[lg][par][q * 4 + kk][lane], mybuf[kk],
                               __ATOMIC_RELAXED, __HIP_MEMORY_SCOPE_WORKGROUP);
    }
}

// ---------------- FC2: leaky(Y) @ W2^T + b2 ----------------
__global__ __launch_bounds__(256) void fc2_kernel(
    const float* __restrict__ Y, const float* __restrict__ W2,
    const float* __restrict__ b2, float* __restrict__ out)
{
    int t = blockIdx.x;
    __shared__ float ys[NODES];
    int tid = threadIdx.x;
    for (int n = tid; n < NODES; n += 256) {
        float v = Y[(size_t)t * NODES + n];
        ys[n] = v > 0.f ? v : SLOPE * v;
    }
    __syncthreads();
    int wave = tid >> 6, lane = tid & 63;
    for (int o = wave; o < OUT_DIM; o += 4) {
        float acc = 0.f;
        const float* w = W2 + o * NODES;
        #pragma unroll
        for (int k = 0; k < 16; ++k) acc += w[lane + k * 64] * ys[lane + k * 64];
        #pragma unroll
        for (int off = 32; off > 0; off >>= 1) acc += __shfl_xor(acc, off);
        if (lane == 0) out[t * OUT_DIM + o] = acc + b2[o];
    }
}

extern "C" void kernel_launch(void* const* d_in, const int* in_sizes, int n_in,
                              void* d_out, int out_size, void* d_ws, size_t ws_size,
                              hipStream_t stream) {
    const float* sim  = (const float*)d_in[0];
    const float* relv = (const float*)d_in[1];
    const float* act  = (const float*)d_in[2];
    const float* W1   = (const float*)d_in[3];
    const float* b1   = (const float*)d_in[4];
    const float* W_ih = (const float*)d_in[5];
    const float* W_hh = (const float*)d_in[6];
    const float* b_ih = (const float*)d_in[7];
    const float* b_hh = (const float*)d_in[8];
    const float* W2   = (const float*)d_in[9];
    const float* b2   = (const float*)d_in[10];
    const float* h0   = (const float*)d_in[11];
    const float* c0   = (const float*)d_in[12];
    float* out = (float*)d_out;

    char* ws = (char*)d_ws;
    float* xbuf = (float*)ws;                                   // 8 MB (FC1 out; later Y4)
    float* xp   = (float*)(ws + (size_t)8 * 1024 * 1024);       // 32 MB (XP, per group)
    float* ya   = (float*)(ws + (size_t)40 * 1024 * 1024);      // 8 MB (Y1)
    u64*   rings = (u64*)(ws + (size_t)48 * 1024 * 1024);       // 640 KB

    // zero rings in-graph every launch -> no stale flags across replays
    hipMemsetAsync(rings, 0, (size_t)LAYERS * RING_D * NODES * sizeof(u64), stream);

    fc1_kernel<<<SEQ, 256, 0, stream>>>(sim, relv, act, W1, b1, xbuf);

    // ---- group [0,1]: 256 blocks x 512 threads ----
    xproj_kernel<<<dim3(4 * NODES / BN, SEQ / BM), 256, 0, stream>>>(
        xbuf, W_ih, b_ih, b_hh, xp);
    {
        int l_base = 0, nl = 2;
        void* args[] = { (void*)&W_ih, (void*)&W_hh, (void*)&b_ih, (void*)&b_hh,
                         (void*)&xp, (void*)&h0, (void*)&c0, (void*)&ya,
                         (void*)&rings, (void*)&l_base, (void*)&nl };
        hipLaunchCooperativeKernel((const void*)lstm_group_kernel,
                                   dim3(256), dim3(512), args, 0, stream);
    }

    // ---- group [2,3,4]: 256 blocks x 768 threads ----
    xproj_kernel<<<dim3(4 * NODES / BN, SEQ / BM), 256, 0, stream>>>(
        ya, W_ih + (size_t)2 * 4 * NODES * NODES,
        b_ih + 2 * 4 * NODES, b_hh + 2 * 4 * NODES, xp);
    {
        int l_base = 2, nl = 3;
        void* args[] = { (void*)&W_ih, (void*)&W_hh, (void*)&b_ih, (void*)&b_hh,
                         (void*)&xp, (void*)&h0, (void*)&c0, (void*)&xbuf,
                         (void*)&rings, (void*)&l_base, (void*)&nl };
        hipLaunchCooperativeKernel((const void*)lstm_group_kernel,
                                   dim3(256), dim3(768), args, 0, stream);
    }

    fc2_kernel<<<SEQ, 256, 0, stream>>>(xbuf, W2, b2, out);
}

// Round 22
// 26292.374 us; speedup vs baseline: 2.4975x; 2.4975x over previous
//
#include <hip/hip_runtime.h>

#define NODES 1024
#define LAYERS 5
#define SEQ 2048
#define IN_DIM 30
#define OUT_DIM 12
#define SLOPE 0.01f
#define RING_D 16
#define MIR_D 4

typedef unsigned long long u64;

__device__ __forceinline__ float sigmoidf_(float x) { return 1.0f / (1.0f + expf(-x)); }

// ---------------- FC1: concat(sim,real,act) @ W1^T + b1, leaky ----------------
__global__ __launch_bounds__(256) void fc1_kernel(
    const float* __restrict__ sim, const float* __restrict__ realv,
    const float* __restrict__ act, const float* __restrict__ W1,
    const float* __restrict__ b1, float* __restrict__ x_out)
{
    int t = blockIdx.x;
    __shared__ float in_s[IN_DIM];
    int tid = threadIdx.x;
    if (tid < 12) in_s[tid] = sim[t * 12 + tid];
    else if (tid < 24) in_s[tid] = realv[t * 12 + (tid - 12)];
    else if (tid < 30) in_s[tid] = act[t * 6 + (tid - 24)];
    __syncthreads();
    for (int n = tid; n < NODES; n += 256) {
        float acc = b1[n];
        const float* w = W1 + n * IN_DIM;
        #pragma unroll
        for (int k = 0; k < IN_DIM; ++k) acc += w[k] * in_s[k];
        x_out[t * NODES + n] = acc > 0.f ? acc : SLOPE * acc;
    }
}

// ---------------- xproj: XP = X @ W^T + (b_ih + b_hh) ----------------
#define BM 64
#define BN 64
#define BK 16

__global__ __launch_bounds__(256) void xproj_kernel(
    const float* __restrict__ X, const float* __restrict__ W,
    const float* __restrict__ bih, const float* __restrict__ bhh,
    float* __restrict__ XP)
{
    const int GN = 4 * NODES;
    int bm = blockIdx.y;
    int bn = blockIdx.x;
    __shared__ float As[BK][BM];
    __shared__ float Bs[BK][BN];
    int tid = threadIdx.x;
    int tx = tid % 16, ty = tid / 16;
    int arow = tid / 4;
    int acol4 = (tid % 4) * 4;
    float acc[4][4] = {};

    for (int k0 = 0; k0 < NODES; k0 += BK) {
        float4 a = *(const float4*)&X[(size_t)(bm * BM + arow) * NODES + k0 + acol4];
        As[acol4 + 0][arow] = a.x; As[acol4 + 1][arow] = a.y;
        As[acol4 + 2][arow] = a.z; As[acol4 + 3][arow] = a.w;
        float4 b = *(const float4*)&W[(size_t)(bn * BN + arow) * NODES + k0 + acol4];
        Bs[acol4 + 0][arow] = b.x; Bs[acol4 + 1][arow] = b.y;
        Bs[acol4 + 2][arow] = b.z; Bs[acol4 + 3][arow] = b.w;
        __syncthreads();
        #pragma unroll
        for (int k = 0; k < BK; ++k) {
            float ra[4], rb[4];
            #pragma unroll
            for (int m = 0; m < 4; ++m) ra[m] = As[k][ty * 4 + m];
            #pragma unroll
            for (int n = 0; n < 4; ++n) rb[n] = Bs[k][tx * 4 + n];
            #pragma unroll
            for (int m = 0; m < 4; ++m)
                #pragma unroll
                for (int n = 0; n < 4; ++n)
                    acc[m][n] += ra[m] * rb[n];
        }
        __syncthreads();
    }
    #pragma unroll
    for (int m = 0; m < 4; ++m) {
        int t = bm * BM + ty * 4 + m;
        int g0 = bn * BN + tx * 4;
        float4 o;
        o.x = acc[m][0] + bih[g0 + 0] + bhh[g0 + 0];
        o.y = acc[m][1] + bih[g0 + 1] + bhh[g0 + 1];
        o.z = acc[m][2] + bih[g0 + 2] + bhh[g0 + 2];
        o.w = acc[m][3] + bih[g0 + 3] + bhh[g0 + 3];
        *(float4*)&XP[(size_t)t * GN + g0] = o;
    }
}

// ---------------- Fused LSTM group (NL=1 or 2): R16 protocol + depth-4 mirrors ----------
// Best-known configuration (R18, 26.30k us). 256 blocks x NL*4 waves, cooperative,
// free-running. Wave w: lg=w>>2, q=w&3, unit j=blockIdx.x*4+q; l=l_base+lg.
//  - lg0 consumes precomputed XP (biases folded); lg1 reads x(t) from mir[0]
//    (LDS, filled by lg0's own-polls) -- no global x-poll.
//  - Each lg quarter-polls its own global ring {flag=t+1,h} u64 slots (relaxed
//    agent atomics, blind pipelined 4-slot sweep), mirrors into mir[lg][t%4]
//    (relaxed workgroup atomics, single writer/slot), then full-reads the mirror.
//  - GATE (lg0, t>=4): wait mir[1] flags >= t-4 before overwriting mir[0][t%4]
//    (slot's previous occupant; lg1's mirror-write precedes its later x-reads).
//  - FINAL FILL (lg0): after loop, gate >= SEQ-4, then mirror ring flag SEQ
//    (lg1's last x-read; omitting this was R14's deadlock).
// Floor analysis (R12/R13/R15/R18/R19 evidence): phase = IC publish->visibility->
// detect RT (~2us, inherent to all-to-all h broadcast through the coherence
// point) + compute; pairwise fusion amortizes to ~2.6us/layer-step. Deeper
// chains hit the >=768-thread VGPR-cap/spill cliff (R17/R20/R21).
__global__ __launch_bounds__(512, 2)
void lstm_group_kernel(
    const float* __restrict__ Wih,   // [L][4N][N] (global base)
    const float* __restrict__ Whh,   // [L][4N][N] (global base)
    const float* __restrict__ bih,   // [L][4N]
    const float* __restrict__ bhh,   // [L][4N]
    const float* __restrict__ XP,    // [SEQ][4N] first-group-layer input proj
    const float* __restrict__ h0,    // [L][N]
    const float* __restrict__ c0,    // [L][N]
    float* __restrict__ Yout,        // [SEQ][N] last-group-layer output
    u64* rings, int l_base, int NL)
{
    __shared__ u64 mir[2][MIR_D][16][64];  // 64KB: [layer][t%4][slot k][lane]

    const int tid = threadIdx.x;
    const int wave = tid >> 6, lane = tid & 63;
    const int lg = wave >> 2;
    const int q = wave & 3;
    const int j = blockIdx.x * 4 + q;
    const int l = l_base + lg;
    const bool first = (lg == 0);
    const bool last  = (lg == NL - 1);

    // ---- stage weights ----
    float whh[4][16];
    {
        const float* wp = Whh + (size_t)l * 4 * NODES * NODES;
        #pragma unroll
        for (int g = 0; g < 4; ++g)
            #pragma unroll
            for (int k = 0; k < 16; ++k)
                whh[g][k] = wp[(size_t)(g * NODES + j) * NODES + lane + k * 64];
    }
    float wih[4][16];
    if (!first) {
        const float* wp = Wih + (size_t)l * 4 * NODES * NODES;
        #pragma unroll
        for (int g = 0; g < 4; ++g)
            #pragma unroll
            for (int k = 0; k < 16; ++k)
                wih[g][k] = wp[(size_t)(g * NODES + j) * NODES + lane + k * 64];
    }
    float bg[4] = {0.f, 0.f, 0.f, 0.f};
    if (!first) {
        #pragma unroll
        for (int g = 0; g < 4; ++g)
            bg[g] = bih[l * 4 * NODES + g * NODES + j] + bhh[l * 4 * NODES + g * NODES + j];
    }

    // zero LDS mirrors (stale flags would fake a match)
    for (int idx = tid; idx < 2 * MIR_D * 16 * 64; idx += blockDim.x)
        ((u64*)mir)[idx] = 0;

    u64* ring_own = rings + (size_t)l * RING_D * NODES;

    float c = c0[l * NODES + j];
    float xpg[4] = {0.f, 0.f, 0.f, 0.f};
    if (first) {
        #pragma unroll
        for (int g = 0; g < 4; ++g) xpg[g] = XP[(size_t)0 * 4 * NODES + g * NODES + j];
    }
    __syncthreads();  // mirrors zeroed

    for (int t = 0; t < SEQ; ++t) {
        float gate[4] = {0.f, 0.f, 0.f, 0.f};

        // ---- own-layer h(t-1): quarter-poll global -> [gate] -> LDS mirror -> full read ----
        if (t == 0) {
            #pragma unroll
            for (int k = 0; k < 16; ++k) {
                float hh = h0[l * NODES + lane + k * 64];
                #pragma unroll
                for (int g = 0; g < 4; ++g) gate[g] += whh[g][k] * hh;
            }
        } else {
            u64* so = ring_own + (size_t)(t % RING_D) * NODES;
            const int par = t & (MIR_D - 1);
            u64 mybuf[4];
            for (;;) {
                #pragma unroll
                for (int kk = 0; kk < 4; ++kk)
                    mybuf[kk] = __hip_atomic_load(&so[lane + (q * 4 + kk) * 64],
                                                  __ATOMIC_RELAXED, __HIP_MEMORY_SCOPE_AGENT);
                bool ok = true;
                #pragma unroll
                for (int kk = 0; kk < 4; ++kk) ok = ok && ((int)(mybuf[kk] >> 32) == t);
                if (ok) break;
            }
            // gate: protect lg1's pending x-read of flag t-4 (same slot, previous occupant)
            if (!last && t >= 4) {
                const int thresh = t - 4;
                for (;;) {
                    bool ok = true;
                    #pragma unroll
                    for (int qq = 0; qq < 4; ++qq) {
                        u64 v = __hip_atomic_load(&mir[lg + 1][par][qq * 4][lane],
                                                  __ATOMIC_RELAXED, __HIP_MEMORY_SCOPE_WORKGROUP);
                        ok = ok && ((int)(v >> 32) >= thresh);
                    }
                    if (ok) break;
                }
            }
            #pragma unroll
            for (int kk = 0; kk < 4; ++kk)
                __hip_atomic_store(&mir[lg][par][q * 4 + kk][lane], mybuf[kk],
                                   __ATOMIC_RELAXED, __HIP_MEMORY_SCOPE_WORKGROUP);
            u64 vo[16];
            for (;;) {
                bool ok = true;
                #pragma unroll
                for (int k = 0; k < 16; ++k) {
                    vo[k] = __hip_atomic_load(&mir[lg][par][k][lane],
                                              __ATOMIC_RELAXED, __HIP_MEMORY_SCOPE_WORKGROUP);
                    ok = ok && ((int)(vo[k] >> 32) == t);
                }
                if (ok) break;
            }
            #pragma unroll
            for (int k = 0; k < 16; ++k) {
                float hh = __uint_as_float((unsigned)vo[k]);
                #pragma unroll
                for (int g = 0; g < 4; ++g) gate[g] += whh[g][k] * hh;
            }
        }

        // ---- prev-layer x(t) = upstream mirror flag t+1 (pure LDS, no global poll) ----
        if (!first) {
            const int par = (t + 1) & (MIR_D - 1);
            u64 vi[16];
            for (;;) {
                bool ok = true;
                #pragma unroll
                for (int k = 0; k < 16; ++k) {
                    vi[k] = __hip_atomic_load(&mir[lg - 1][par][k][lane],
                                              __ATOMIC_RELAXED, __HIP_MEMORY_SCOPE_WORKGROUP);
                    ok = ok && ((int)(vi[k] >> 32) == t + 1);
                }
                if (ok) break;
            }
            #pragma unroll
            for (int k = 0; k < 16; ++k) {
                float xx = __uint_as_float((unsigned)vi[k]);
                #pragma unroll
                for (int g = 0; g < 4; ++g) gate[g] += wih[g][k] * xx;
            }
        }

        // ---- reduce + activations ----
        #pragma unroll
        for (int g = 0; g < 4; ++g) {
            float acc = gate[g];
            #pragma unroll
            for (int off = 32; off > 0; off >>= 1) acc += __shfl_xor(acc, off);
            gate[g] = acc + (first ? xpg[g] : bg[g]);
        }

        float ig = sigmoidf_(gate[0]);
        float fg = sigmoidf_(gate[1]);
        float gg = tanhf(gate[2]);
        float og = sigmoidf_(gate[3]);
        c = fg * c + ig * gg;
        float h = og * tanhf(c);

        if (lane == 0) {
            u64 pv = ((u64)(unsigned)(t + 1) << 32) | (u64)__float_as_uint(h);
            __hip_atomic_store(&ring_own[(size_t)((t + 1) % RING_D) * NODES + j], pv,
                               __ATOMIC_RELAXED, __HIP_MEMORY_SCOPE_AGENT);
            if (last) Yout[(size_t)t * NODES + j] = h;
        }

        if (first && t + 1 < SEQ) {
            #pragma unroll
            for (int g = 0; g < 4; ++g)
                xpg[g] = XP[(size_t)(t + 1) * 4 * NODES + g * NODES + j];
        }
    }

    // ---- FINAL FILL (lg0 of NL2 only): mirror ring flag SEQ for lg1's last x-read ----
    if (!last) {
        const int par = SEQ & (MIR_D - 1);
        const int thresh = SEQ - 4;
        for (;;) {  // gate: lg1 past its x-read of flag SEQ-4 (slot's previous occupant)
            bool ok = true;
            #pragma unroll
            for (int qq = 0; qq < 4; ++qq) {
                u64 v = __hip_atomic_load(&mir[lg + 1][par][qq * 4][lane],
                                          __ATOMIC_RELAXED, __HIP_MEMORY_SCOPE_WORKGROUP);
                ok = ok && ((int)(v >> 32) >= thresh);
            }
            if (ok) break;
        }
        u64* so = ring_own + (size_t)(SEQ % RING_D) * NODES;
        u64 mybuf[4];
        for (;;) {
            #pragma unroll
            for (int kk = 0; kk < 4; ++kk)
                mybuf[kk] = __hip_atomic_load(&so[lane + (q * 4 + kk) * 64],
                                              __ATOMIC_RELAXED, __HIP_MEMORY_SCOPE_AGENT);
            bool ok = true;
            #pragma unroll
            for (int kk = 0; kk < 4; ++kk) ok = ok && ((int)(mybuf[kk] >> 32) == SEQ);
            if (ok) break;
        }
        #pragma unroll
        for (int kk = 0; kk < 4; ++kk)
            __hip_atomic_store(&mir[lg][par][q * 4 + kk][lane], mybuf[kk],
                               __ATOMIC_RELAXED, __HIP_MEMORY_SCOPE_WORKGROUP);
    }
}

// ---------------- FC2: leaky(Y) @ W2^T + b2 ----------------
__global__ __launch_bounds__(256) void fc2_kernel(
    const float* __restrict__ Y, const float* __restrict__ W2,
    const float* __restrict__ b2, float* __restrict__ out)
{
    int t = blockIdx.x;
    __shared__ float ys[NODES];
    int tid = threadIdx.x;
    for (int n = tid; n < NODES; n += 256) {
        float v = Y[(size_t)t * NODES + n];
        ys[n] = v > 0.f ? v : SLOPE * v;
    }
    __syncthreads();
    int wave = tid >> 6, lane = tid & 63;
    for (int o = wave; o < OUT_DIM; o += 4) {
        float acc = 0.f;
        const float* w = W2 + o * NODES;
        #pragma unroll
        for (int k = 0; k < 16; ++k) acc += w[lane + k * 64] * ys[lane + k * 64];
        #pragma unroll
        for (int off = 32; off > 0; off >>= 1) acc += __shfl_xor(acc, off);
        if (lane == 0) out[t * OUT_DIM + o] = acc + b2[o];
    }
}

extern "C" void kernel_launch(void* const* d_in, const int* in_sizes, int n_in,
                              void* d_out, int out_size, void* d_ws, size_t ws_size,
                              hipStream_t stream) {
    const float* sim  = (const float*)d_in[0];
    const float* relv = (const float*)d_in[1];
    const float* act  = (const float*)d_in[2];
    const float* W1   = (const float*)d_in[3];
    const float* b1   = (const float*)d_in[4];
    const float* W_ih = (const float*)d_in[5];
    const float* W_hh = (const float*)d_in[6];
    const float* b_ih = (const float*)d_in[7];
    const float* b_hh = (const float*)d_in[8];
    const float* W2   = (const float*)d_in[9];
    const float* b2   = (const float*)d_in[10];
    const float* h0   = (const float*)d_in[11];
    const float* c0   = (const float*)d_in[12];
    float* out = (float*)d_out;

    char* ws = (char*)d_ws;
    float* xbuf = (float*)ws;                                   // 8 MB (FC1 out; later Y4)
    float* xp   = (float*)(ws + (size_t)8 * 1024 * 1024);       // 32 MB (XP, per group)
    float* ya   = (float*)(ws + (size_t)40 * 1024 * 1024);      // 8 MB (Y1, then Y3)
    u64*   rings = (u64*)(ws + (size_t)48 * 1024 * 1024);       // 640 KB

    // zero rings in-graph every launch -> no stale flags across replays
    hipMemsetAsync(rings, 0, (size_t)LAYERS * RING_D * NODES * sizeof(u64), stream);

    fc1_kernel<<<SEQ, 256, 0, stream>>>(sim, relv, act, W1, b1, xbuf);

    // ---- group [0,1]: 256 blocks x 512 threads ----
    xproj_kernel<<<dim3(4 * NODES / BN, SEQ / BM), 256, 0, stream>>>(
        xbuf, W_ih, b_ih, b_hh, xp);
    {
        int l_base = 0, nl = 2;
        void* args[] = { (void*)&W_ih, (void*)&W_hh, (void*)&b_ih, (void*)&b_hh,
                         (void*)&xp, (void*)&h0, (void*)&c0, (void*)&ya,
                         (void*)&rings, (void*)&l_base, (void*)&nl };
        hipLaunchCooperativeKernel((const void*)lstm_group_kernel,
                                   dim3(256), dim3(512), args, 0, stream);
    }

    // ---- group [2,3] ----
    xproj_kernel<<<dim3(4 * NODES / BN, SEQ / BM), 256, 0, stream>>>(
        ya, W_ih + (size_t)2 * 4 * NODES * NODES,
        b_ih + 2 * 4 * NODES, b_hh + 2 * 4 * NODES, xp);
    {
        int l_base = 2, nl = 2;
        void* args[] = { (void*)&W_ih, (void*)&W_hh, (void*)&b_ih, (void*)&b_hh,
                         (void*)&xp, (void*)&h0, (void*)&c0, (void*)&ya,
                         (void*)&rings, (void*)&l_base, (void*)&nl };
        hipLaunchCooperativeKernel((const void*)lstm_group_kernel,
                                   dim3(256), dim3(512), args, 0, stream);
    }

    // ---- group [4] ----
    xproj_kernel<<<dim3(4 * NODES / BN, SEQ / BM), 256, 0, stream>>>(
        ya, W_ih + (size_t)4 * 4 * NODES * NODES,
        b_ih + 4 * 4 * NODES, b_hh + 4 * 4 * NODES, xp);
    {
        int l_base = 4, nl = 1;
        void* args[] = { (void*)&W_ih, (void*)&W_hh, (void*)&b_ih, (void*)&b_hh,
                         (void*)&xp, (void*)&h0, (void*)&c0, (void*)&xbuf,
                         (void*)&rings, (void*)&l_base, (void*)&nl };
        hipLaunchCooperativeKernel((const void*)lstm_group_kernel,
                                   dim3(256), dim3(256), args, 0, stream);
    }

    fc2_kernel<<<SEQ, 256, 0, stream>>>(xbuf, W2, b2, out);
}